// Round 1
// baseline (2977.661 us; speedup 1.0000x reference)
//
#include <hip/hip_runtime.h>

#define W_CLS 16
#define SHOT  8
#define C_CH  128
#define HW    1024
#define NSAMP (SHOT*HW)   /* 8192 */
#define B_Q   256

// ---------------- kernel 1: per-(w,c) channel means over 8192 support pixels ----
__global__ __launch_bounds__(256) void mean_kernel(const float* __restrict__ x2,
                                                   float* __restrict__ mean) {
    int wc = blockIdx.x;              // 0..2047 : w*128 + c
    int w  = wc >> 7, c = wc & 127;
    const float* base = x2 + ((size_t)(w * SHOT) * C_CH + c) * HW;
    int tid = threadIdx.x;
    float sum = 0.f;
    for (int s = 0; s < SHOT; ++s) {
        const float* row = base + (size_t)s * C_CH * HW;
        for (int p = tid; p < HW; p += 256) sum += row[p];
    }
    for (int off = 32; off; off >>= 1) sum += __shfl_down(sum, off, 64);
    __shared__ float red[4];
    int lane = tid & 63, wv = tid >> 6;
    if (lane == 0) red[wv] = sum;
    __syncthreads();
    if (tid == 0) mean[wc] = (red[0] + red[1] + red[2] + red[3]) * (1.0f / NSAMP);
}

// ---------------- kernel 2: gram tiles + mean correction -> covariance ----------
// grid = 16 * 4 * 4, block 256 (16x16 threads, 2x2 micro-tile) -> 32x32 cova tile
__global__ __launch_bounds__(256) void cova_kernel(const float* __restrict__ x2,
                                                   const float* __restrict__ mean,
                                                   float* __restrict__ cova) {
    int bid = blockIdx.x;
    int w  = bid >> 4;
    int c0 = ((bid >> 2) & 3) * 32;
    int d0 = (bid & 3) * 32;

    __shared__ float As[32][33];
    __shared__ float Bs[32][33];

    int tid = threadIdx.x;
    int ty = tid >> 4, tx = tid & 15;
    int lr = tid >> 3, lc = (tid & 7) * 4;      // loader: row 0..31, col quad

    const float* base = x2 + (size_t)w * SHOT * C_CH * HW;
    float acc00 = 0.f, acc01 = 0.f, acc10 = 0.f, acc11 = 0.f;

    for (int k0 = 0; k0 < NSAMP; k0 += 32) {
        int s = k0 >> 10, p = k0 & 1023;
        const float4 a4 = *(const float4*)(base + ((size_t)s * C_CH + (c0 + lr)) * HW + p + lc);
        const float4 b4 = *(const float4*)(base + ((size_t)s * C_CH + (d0 + lr)) * HW + p + lc);
        As[lr][lc+0] = a4.x; As[lr][lc+1] = a4.y; As[lr][lc+2] = a4.z; As[lr][lc+3] = a4.w;
        Bs[lr][lc+0] = b4.x; Bs[lr][lc+1] = b4.y; Bs[lr][lc+2] = b4.z; Bs[lr][lc+3] = b4.w;
        __syncthreads();
        #pragma unroll
        for (int kk = 0; kk < 32; ++kk) {
            float a0 = As[ty*2][kk],   a1 = As[ty*2+1][kk];
            float b0 = Bs[tx*2][kk],   b1 = Bs[tx*2+1][kk];
            acc00 = fmaf(a0, b0, acc00);
            acc01 = fmaf(a0, b1, acc01);
            acc10 = fmaf(a1, b0, acc10);
            acc11 = fmaf(a1, b1, acc11);
        }
        __syncthreads();
    }

    const float inv = 1.0f / (NSAMP - 1);
    int c = c0 + ty * 2, d = d0 + tx * 2;
    float mc0 = mean[w*128 + c],     mc1 = mean[w*128 + c + 1];
    float md0 = mean[w*128 + d],     md1 = mean[w*128 + d + 1];
    float* o = cova + ((size_t)w * 128 + c) * 128 + d;
    o[0]       = (acc00 - (float)NSAMP * mc0 * md0) * inv;
    o[1]       = (acc01 - (float)NSAMP * mc0 * md1) * inv;
    o[128]     = (acc10 - (float)NSAMP * mc1 * md0) * inv;
    o[129]     = (acc11 - (float)NSAMP * mc1 * md1) * inv;
}

// ---------------- kernel 3: reciprocal L2 norm per (b,c) row of 1024 ------------
__global__ __launch_bounds__(256) void rnorm_kernel(const float* __restrict__ x1,
                                                    float* __restrict__ rn) {
    int row  = blockIdx.x * 4 + (threadIdx.x >> 6);   // b*128 + c
    int lane = threadIdx.x & 63;
    const float4* p = (const float4*)(x1 + (size_t)row * HW);
    float s = 0.f;
    #pragma unroll
    for (int it = 0; it < 4; ++it) {
        float4 v = p[lane + it * 64];
        s += v.x*v.x + v.y*v.y + v.z*v.z + v.w*v.w;
    }
    for (int off = 32; off; off >>= 1) s += __shfl_down(s, off, 64);
    if (lane == 0) rn[row] = 1.0f / sqrtf(s);
}

// ---------------- kernel 4: sim[b,w,i] = qn_i^T Cova[w] qn_i --------------------
// block = (b, w, 256-wide i tile); one thread per pixel i; q column in registers.
__global__ __launch_bounds__(256) void sim_kernel(const float* __restrict__ x1,
                                                  const float* __restrict__ cova,
                                                  const float* __restrict__ rn,
                                                  float* __restrict__ out) {
    int bid   = blockIdx.x;
    int itile = bid & 3;
    int w     = (bid >> 2) & 15;
    int b     = bid >> 6;
    int i     = itile * 256 + threadIdx.x;

    const float* qb  = x1 + (size_t)b * C_CH * HW + i;
    const float* rnb = rn + b * 128;

    float qreg[128];
    #pragma unroll
    for (int c = 0; c < 128; ++c) qreg[c] = qb[(size_t)c * HW] * rnb[c];

    const float* Cw = cova + (size_t)w * 128 * 128;
    float sim = 0.f;
    for (int c = 0; c < 128; ++c) {
        const float* row = Cw + c * 128;
        float t0 = 0.f, t1 = 0.f, t2 = 0.f, t3 = 0.f;
        #pragma unroll
        for (int d = 0; d < 128; d += 4) {
            t0 = fmaf(row[d+0], qreg[d+0], t0);
            t1 = fmaf(row[d+1], qreg[d+1], t1);
            t2 = fmaf(row[d+2], qreg[d+2], t2);
            t3 = fmaf(row[d+3], qreg[d+3], t3);
        }
        // re-read q_c from global (L1-hit) to avoid runtime register indexing
        float qc = qb[(size_t)c * HW] * rnb[c];
        sim = fmaf((t0 + t1) + (t2 + t3), qc, sim);
    }
    out[((size_t)b * W_CLS + w) * HW + i] = sim;
}

extern "C" void kernel_launch(void* const* d_in, const int* in_sizes, int n_in,
                              void* d_out, int out_size, void* d_ws, size_t ws_size,
                              hipStream_t stream) {
    const float* x1 = (const float*)d_in[0];   // [256,128,32,32]
    const float* x2 = (const float*)d_in[1];   // [16,8,128,32,32]
    float* out = (float*)d_out;                // [256, 16*1024]

    float* ws   = (float*)d_ws;
    float* cova = ws;                          // 16*128*128 = 262144 floats
    float* mean = cova + (size_t)W_CLS * C_CH * C_CH;   // 2048 floats
    float* rn   = mean + W_CLS * C_CH;                  // 32768 floats

    mean_kernel <<<W_CLS * C_CH,          256, 0, stream>>>(x2, mean);
    cova_kernel <<<W_CLS * 16,            256, 0, stream>>>(x2, mean, cova);
    rnorm_kernel<<<B_Q * C_CH / 4,        256, 0, stream>>>(x1, rn);
    sim_kernel  <<<B_Q * W_CLS * (HW/256),256, 0, stream>>>(x1, cova, rn, out);
}

// Round 2
// 761.762 us; speedup vs baseline: 3.9089x; 3.9089x over previous
//
#include <hip/hip_runtime.h>

typedef _Float16 half8 __attribute__((ext_vector_type(8)));
typedef _Float16 half4 __attribute__((ext_vector_type(4)));
typedef float    f32x4 __attribute__((ext_vector_type(4)));

#define W_CLS 16
#define SHOT  8
#define C_CH  128
#define HW    1024
#define NSAMP (SHOT*HW)   /* 8192 */
#define B_Q   256
#define NT    128          /* i-pixels per sim block */
#define LDQ   136          /* qT row stride (fp16 elems): 272 B, 16B-aligned */

// ---------------- kernel 1: per-(w,c) channel means over 8192 support pixels ----
__global__ __launch_bounds__(256) void mean_kernel(const float* __restrict__ x2,
                                                   float* __restrict__ mean) {
    int wc = blockIdx.x;              // w*128 + c
    int w  = wc >> 7, c = wc & 127;
    const float* base = x2 + ((size_t)(w * SHOT) * C_CH + c) * HW;
    int tid = threadIdx.x;
    float sum = 0.f;
    for (int s = 0; s < SHOT; ++s) {
        const float* row = base + (size_t)s * C_CH * HW;
        for (int p = tid; p < HW; p += 256) sum += row[p];
    }
    for (int off = 32; off; off >>= 1) sum += __shfl_down(sum, off, 64);
    __shared__ float red[4];
    int lane = tid & 63, wv = tid >> 6;
    if (lane == 0) red[wv] = sum;
    __syncthreads();
    if (tid == 0) mean[wc] = (red[0] + red[1] + red[2] + red[3]) * (1.0f / NSAMP);
}

// ---------------- kernel 2: gram tiles + mean correction -> fp16 covariance -----
__global__ __launch_bounds__(256) void cova_kernel(const float* __restrict__ x2,
                                                   const float* __restrict__ mean,
                                                   _Float16* __restrict__ covah) {
    int bid = blockIdx.x;
    int w  = bid >> 4;
    int c0 = ((bid >> 2) & 3) * 32;
    int d0 = (bid & 3) * 32;

    __shared__ float As[32][33];
    __shared__ float Bs[32][33];

    int tid = threadIdx.x;
    int ty = tid >> 4, tx = tid & 15;
    int lr = tid >> 3, lc = (tid & 7) * 4;

    const float* base = x2 + (size_t)w * SHOT * C_CH * HW;
    float acc00 = 0.f, acc01 = 0.f, acc10 = 0.f, acc11 = 0.f;

    for (int k0 = 0; k0 < NSAMP; k0 += 32) {
        int s = k0 >> 10, p = k0 & 1023;
        const float4 a4 = *(const float4*)(base + ((size_t)s * C_CH + (c0 + lr)) * HW + p + lc);
        const float4 b4 = *(const float4*)(base + ((size_t)s * C_CH + (d0 + lr)) * HW + p + lc);
        As[lr][lc+0] = a4.x; As[lr][lc+1] = a4.y; As[lr][lc+2] = a4.z; As[lr][lc+3] = a4.w;
        Bs[lr][lc+0] = b4.x; Bs[lr][lc+1] = b4.y; Bs[lr][lc+2] = b4.z; Bs[lr][lc+3] = b4.w;
        __syncthreads();
        #pragma unroll
        for (int kk = 0; kk < 32; ++kk) {
            float a0 = As[ty*2][kk],   a1 = As[ty*2+1][kk];
            float b0 = Bs[tx*2][kk],   b1 = Bs[tx*2+1][kk];
            acc00 = fmaf(a0, b0, acc00);
            acc01 = fmaf(a0, b1, acc01);
            acc10 = fmaf(a1, b0, acc10);
            acc11 = fmaf(a1, b1, acc11);
        }
        __syncthreads();
    }

    const float inv = 1.0f / (NSAMP - 1);
    int c = c0 + ty * 2, d = d0 + tx * 2;
    float mc0 = mean[w*128 + c],     mc1 = mean[w*128 + c + 1];
    float md0 = mean[w*128 + d],     md1 = mean[w*128 + d + 1];
    _Float16* o = covah + ((size_t)w * 128 + c) * 128 + d;
    o[0]   = (_Float16)((acc00 - (float)NSAMP * mc0 * md0) * inv);
    o[1]   = (_Float16)((acc01 - (float)NSAMP * mc0 * md1) * inv);
    o[128] = (_Float16)((acc10 - (float)NSAMP * mc1 * md0) * inv);
    o[129] = (_Float16)((acc11 - (float)NSAMP * mc1 * md1) * inv);
}

// ---------------- kernel 3: reciprocal L2 norm per (b,c) row of 1024 ------------
__global__ __launch_bounds__(256) void rnorm_kernel(const float* __restrict__ x1,
                                                    float* __restrict__ rn) {
    int row  = blockIdx.x * 4 + (threadIdx.x >> 6);   // b*128 + c
    int lane = threadIdx.x & 63;
    const float4* p = (const float4*)(x1 + (size_t)row * HW);
    float s = 0.f;
    #pragma unroll
    for (int it = 0; it < 4; ++it) {
        float4 v = p[lane + it * 64];
        s += v.x*v.x + v.y*v.y + v.z*v.z + v.w*v.w;
    }
    for (int off = 32; off; off >>= 1) s += __shfl_down(s, off, 64);
    if (lane == 0) rn[row] = 1.0f / sqrtf(s);
}

// ---------------- kernel 4: MFMA sim: per (b, i-tile) block, loop w -------------
// 512 threads = 8 waves = 2 (d-half) x 4 (i-quarter). Per wave: 4 M-tiles x 2 N-tiles.
__global__ __launch_bounds__(512) void sim_kernel(const float* __restrict__ x1,
                                                  const _Float16* __restrict__ Ch,
                                                  const float* __restrict__ rn,
                                                  float* __restrict__ out) {
    __shared__ _Float16 qT[NT][LDQ];     // q transposed: qT[i][c], fp16, normalized
    __shared__ float simbuf[2][NT];

    int tid = threadIdx.x;
    int bq  = blockIdx.x;
    int b   = bq >> 3;
    int i0  = (bq & 7) * NT;

    // ---- prologue: stage normalized q tile, transposed, fp16 ----
    {
        int c  = tid >> 2;
        int iq = (tid & 3) * 32;
        const float* src = x1 + ((size_t)b * C_CH + c) * HW + i0 + iq;
        float scale = rn[b * C_CH + c];
        #pragma unroll
        for (int j4 = 0; j4 < 8; ++j4) {
            f32x4 v = *(const f32x4*)(src + j4 * 4);
            qT[iq + j4*4 + 0][c] = (_Float16)(v.x * scale);
            qT[iq + j4*4 + 1][c] = (_Float16)(v.y * scale);
            qT[iq + j4*4 + 2][c] = (_Float16)(v.z * scale);
            qT[iq + j4*4 + 3][c] = (_Float16)(v.w * scale);
        }
    }
    __syncthreads();

    int lane = tid & 63;
    int wv   = tid >> 6;
    int mh   = wv >> 2;           // d-half: 0/1
    int nq   = wv & 3;            // i-quarter
    int d0w  = mh * 64;
    int iw   = nq * 32;
    int lr   = lane & 15;
    int lg   = lane >> 4;

    // ---- preload diag q quads (w-independent): q[d, i] for lane's frag slots ----
    float qd[4][2][4];
    #pragma unroll
    for (int m = 0; m < 4; ++m)
        #pragma unroll
        for (int n = 0; n < 2; ++n) {
            half4 hq = *(const half4*)&qT[iw + n*16 + lr][d0w + m*16 + lg*4];
            qd[m][n][0] = (float)hq[0];
            qd[m][n][1] = (float)hq[1];
            qd[m][n][2] = (float)hq[2];
            qd[m][n][3] = (float)hq[3];
        }

    for (int w = 0; w < W_CLS; ++w) {
        const _Float16* Cw = Ch + (size_t)w * C_CH * C_CH;

        // A frags: C (symmetric) rows, contiguous 16B loads, L2-resident
        half8 A[4][4];
        #pragma unroll
        for (int m = 0; m < 4; ++m)
            #pragma unroll
            for (int k = 0; k < 4; ++k)
                A[m][k] = *(const half8*)(Cw + (size_t)(d0w + m*16 + lr) * C_CH + k*32 + lg*8);

        f32x4 acc[4][2];
        #pragma unroll
        for (int m = 0; m < 4; ++m)
            #pragma unroll
            for (int n = 0; n < 2; ++n)
                acc[m][n] = (f32x4){0.f, 0.f, 0.f, 0.f};

        #pragma unroll
        for (int k = 0; k < 4; ++k) {
            #pragma unroll
            for (int n = 0; n < 2; ++n) {
                half8 Bf = *(const half8*)&qT[iw + n*16 + lr][k*32 + lg*8];
                #pragma unroll
                for (int m = 0; m < 4; ++m)
                    acc[m][n] = __builtin_amdgcn_mfma_f32_16x16x32_f16(A[m][k], Bf, acc[m][n], 0, 0, 0);
            }
        }

        // ---- diag contraction: sim_partial[i] = sum_d q[d,i] * T[d,i] ----
        float s0 = 0.f, s1 = 0.f;
        #pragma unroll
        for (int m = 0; m < 4; ++m) {
            #pragma unroll
            for (int r = 0; r < 4; ++r) {
                s0 = fmaf(qd[m][0][r], acc[m][0][r], s0);
                s1 = fmaf(qd[m][1][r], acc[m][1][r], s1);
            }
        }
        s0 += __shfl_xor(s0, 16); s0 += __shfl_xor(s0, 32);
        s1 += __shfl_xor(s1, 16); s1 += __shfl_xor(s1, 32);
        if (lane < 16) {
            simbuf[mh][iw + 0*16 + lane] = s0;
            simbuf[mh][iw + 1*16 + lane] = s1;
        }
        __syncthreads();
        if (tid < NT)
            out[((size_t)b * W_CLS + w) * HW + i0 + tid] = simbuf[0][tid] + simbuf[1][tid];
        __syncthreads();
    }
}

extern "C" void kernel_launch(void* const* d_in, const int* in_sizes, int n_in,
                              void* d_out, int out_size, void* d_ws, size_t ws_size,
                              hipStream_t stream) {
    const float* x1 = (const float*)d_in[0];   // [256,128,32,32]
    const float* x2 = (const float*)d_in[1];   // [16,8,128,32,32]
    float* out = (float*)d_out;                // [256, 16*1024]

    float* ws   = (float*)d_ws;
    float* mean = ws;                                   // 2048 floats
    float* rn   = mean + W_CLS * C_CH;                  // 32768 floats
    _Float16* Ch = (_Float16*)(rn + B_Q * C_CH);        // 16*128*128 fp16 = 512 KB

    mean_kernel <<<W_CLS * C_CH,    256, 0, stream>>>(x2, mean);
    cova_kernel <<<W_CLS * 16,      256, 0, stream>>>(x2, mean, Ch);
    rnorm_kernel<<<B_Q * C_CH / 4,  256, 0, stream>>>(x1, rn);
    sim_kernel  <<<B_Q * (HW / NT), 512, 0, stream>>>(x1, Ch, rn, out);
}

// Round 3
// 226.357 us; speedup vs baseline: 13.1547x; 3.3653x over previous
//
#include <hip/hip_runtime.h>

typedef _Float16 half8 __attribute__((ext_vector_type(8)));
typedef _Float16 half4 __attribute__((ext_vector_type(4)));
typedef float    f32x4 __attribute__((ext_vector_type(4)));

#define W_CLS 16
#define SHOT  8
#define C_CH  128
#define HW    1024
#define NSAMP (SHOT*HW)   /* 8192 */
#define B_Q   256

// async global->LDS, 16B per lane; LDS dest = wave-uniform base (+lane*16 by HW)
__device__ __forceinline__ void gload_lds16(const _Float16* g, _Float16* l) {
    __builtin_amdgcn_global_load_lds((const __attribute__((address_space(1))) unsigned int*)g,
                                     (__attribute__((address_space(3))) unsigned int*)l,
                                     16, 0, 0);
}

// ================= primary path =================

// ---- cova_part: per (w, k-split) partial gram via fp16 MFMA + mean partials ----
// grid 256 = 16 w x 16 ks (ks = shot*2 + p-half, K=512 per block), block 512
__global__ __launch_bounds__(512) void cova_part(const float* __restrict__ x2,
                                                 float* __restrict__ PG,
                                                 float* __restrict__ pmean) {
    __shared__ _Float16 XT[2][128*72];   // [c][p] fp16, pad 72 (conflict-free frags)
    __shared__ float mred[128][4];
    int tid = threadIdx.x;
    int w = blockIdx.x >> 4, ks = blockIdx.x & 15;
    int s = ks >> 1, p00 = (ks & 1) * 512;
    int c = tid >> 2, ph = (tid & 3) * 16;
    const float* src = x2 + (((size_t)(w*SHOT + s))*C_CH + c)*HW + p00 + ph;
    int lane = tid & 63, wv = tid >> 6;
    int lr = lane & 15, lg = lane >> 4;
    int mt0 = (wv & 3)*2, nt0 = (wv >> 2)*4;

    float msum = 0.f;
    f32x4 acc[2][4];
    #pragma unroll
    for (int mm = 0; mm < 2; ++mm)
        #pragma unroll
        for (int nn = 0; nn < 4; ++nn) acc[mm][nn] = (f32x4){0.f,0.f,0.f,0.f};

    float4 rg[4];
    #pragma unroll
    for (int j = 0; j < 4; ++j) rg[j] = *(const float4*)(src + j*4);
    #pragma unroll
    for (int j = 0; j < 4; ++j) {
        msum += rg[j].x + rg[j].y + rg[j].z + rg[j].w;
        half4 h = {(_Float16)rg[j].x, (_Float16)rg[j].y, (_Float16)rg[j].z, (_Float16)rg[j].w};
        *(half4*)(&XT[0][c*72 + ph + j*4]) = h;
    }
    __syncthreads();

    for (int ch = 0; ch < 8; ++ch) {
        int buf = ch & 1;
        if (ch < 7) {
            #pragma unroll
            for (int j = 0; j < 4; ++j) rg[j] = *(const float4*)(src + (ch+1)*64 + j*4);
        }
        const _Float16* xb = XT[buf];
        #pragma unroll
        for (int kk = 0; kk < 2; ++kk) {
            half8 Bv[4], Av[2];
            #pragma unroll
            for (int nn = 0; nn < 4; ++nn)
                Bv[nn] = *(const half8*)(xb + ((nt0+nn)*16 + lr)*72 + kk*32 + lg*8);
            #pragma unroll
            for (int mm = 0; mm < 2; ++mm)
                Av[mm] = *(const half8*)(xb + ((mt0+mm)*16 + lr)*72 + kk*32 + lg*8);
            #pragma unroll
            for (int mm = 0; mm < 2; ++mm)
                #pragma unroll
                for (int nn = 0; nn < 4; ++nn)
                    acc[mm][nn] = __builtin_amdgcn_mfma_f32_16x16x32_f16(Av[mm], Bv[nn], acc[mm][nn], 0,0,0);
        }
        if (ch < 7) {
            #pragma unroll
            for (int j = 0; j < 4; ++j) {
                msum += rg[j].x + rg[j].y + rg[j].z + rg[j].w;
                half4 h = {(_Float16)rg[j].x, (_Float16)rg[j].y, (_Float16)rg[j].z, (_Float16)rg[j].w};
                *(half4*)(&XT[buf^1][c*72 + ph + j*4]) = h;
            }
        }
        __syncthreads();
    }

    mred[c][tid & 3] = msum;
    __syncthreads();
    if (tid < 128)
        pmean[((size_t)w*16 + ks)*128 + tid] = mred[tid][0]+mred[tid][1]+mred[tid][2]+mred[tid][3];

    float* pg = PG + ((size_t)w*16 + ks)*16384;
    #pragma unroll
    for (int mm = 0; mm < 2; ++mm)
        #pragma unroll
        for (int nn = 0; nn < 4; ++nn)
            #pragma unroll
            for (int r = 0; r < 4; ++r) {
                int cr = (mt0+mm)*16 + lg*4 + r;
                int d  = (nt0+nn)*16 + lr;
                pg[cr*128 + d] = acc[mm][nn][r];
            }
}

// ---- cova_reduce: sum 16 partials, mean-correct, fp16 store -------------------
// grid 128 = 16 w x 8 row-groups, block 256
__global__ __launch_bounds__(256) void cova_reduce(const float* __restrict__ PG,
                                                   const float* __restrict__ pmean,
                                                   _Float16* __restrict__ Ch) {
    __shared__ float ms[128];
    int t = threadIdx.x;
    int w = blockIdx.x >> 3, rg = blockIdx.x & 7;
    if (t < 128) {
        float sum = 0.f;
        for (int ks = 0; ks < 16; ++ks) sum += pmean[((size_t)w*16 + ks)*128 + t];
        ms[t] = sum * (1.0f/NSAMP);
    }
    __syncthreads();
    const float* pg = PG + (size_t)w*16*16384;
    #pragma unroll
    for (int it = 0; it < 8; ++it) {
        int e = it*256 + t;
        int c = rg*16 + (e >> 7), d = e & 127;
        float g = 0.f;
        for (int ks = 0; ks < 16; ++ks) g += pg[(size_t)ks*16384 + c*128 + d];
        Ch[((size_t)w*128 + c)*128 + d] =
            (_Float16)((g - (float)NSAMP*ms[c]*ms[d]) * (1.0f/(NSAMP-1)));
    }
}

// ---- rnorm: reciprocal L2 norm per (b,c) row of 1024 --------------------------
__global__ __launch_bounds__(256) void rnorm_kernel(const float* __restrict__ x1,
                                                    float* __restrict__ rn) {
    int row  = blockIdx.x * 4 + (threadIdx.x >> 6);
    int lane = threadIdx.x & 63;
    const float4* p = (const float4*)(x1 + (size_t)row * HW);
    float s = 0.f;
    #pragma unroll
    for (int it = 0; it < 4; ++it) {
        float4 v = p[lane + it * 64];
        s += v.x*v.x + v.y*v.y + v.z*v.z + v.w*v.w;
    }
    for (int off = 32; off; off >>= 1) s += __shfl_down(s, off, 64);
    if (lane == 0) rn[row] = 1.0f / sqrtf(s);
}

// ---- qconv: normalized fp16 q, transposed [b][i][c] with XOR-pre-swizzle ------
// grid 4096 = 256 b x 16 i-chunks of 64, block 256 (4 c-groups x 64 i-lanes)
__global__ __launch_bounds__(256) void qconv_kernel(const float* __restrict__ x1,
                                                    const float* __restrict__ rn,
                                                    _Float16* __restrict__ qhT) {
    int t = threadIdx.x; int lane = t & 63; int cg = t >> 6;
    int bid = blockIdx.x; int b = bid >> 4; int i0 = (bid & 15) * 64;
    int i = i0 + lane;
    const float* xb  = x1 + (size_t)b * C_CH * HW;
    const float* rnb = rn + b * C_CH;
    _Float16 hb[32];
    #pragma unroll
    for (int cc = 0; cc < 32; ++cc) {
        int c = cg*32 + cc;
        hb[cc] = (_Float16)(xb[(size_t)c * HW + i] * rnb[c]);
    }
    _Float16* orow = qhT + ((size_t)b * HW + i) * C_CH;
    #pragma unroll
    for (int j8 = 0; j8 < 4; ++j8) {
        half8 h8;
        #pragma unroll
        for (int e = 0; e < 8; ++e) h8[e] = hb[j8*8 + e];
        int c0 = (cg*32 + j8*8) ^ ((lane & 7) << 3);
        *(half8*)(orow + c0) = h8;
    }
}

// ---- sim: M=(w,d) decomposition; C in regs once; i-chunks double-buffered -----
// grid 1024 = 256 b x 4 w-quads; block 512 = 8 waves (4 w x 2 d-halves)
__global__ __launch_bounds__(512) void sim_kernel(const _Float16* __restrict__ qhT,
                                                  const _Float16* __restrict__ Ch,
                                                  float* __restrict__ out) {
    __shared__ _Float16 qTb[2][64*128];
    __shared__ float simbuf[8][64];
    int tid = threadIdx.x;
    int lane = tid & 63, wv = tid >> 6;
    int lr = lane & 15, lg = lane >> 4;
    int b = blockIdx.x >> 2, wq = blockIdx.x & 3;
    int w_l = wv >> 1, dh = wv & 1;
    int w = wq*4 + w_l;

    const _Float16* qrows = qhT + (size_t)b * HW * C_CH;

    // issue stage chunk 0 -> buf 0
    {
        const _Float16* g = qrows + wv*1024 + lane*8;
        #pragma unroll
        for (int o = 0; o < 2; ++o)
            gload_lds16(g + o*512, &qTb[0][wv*1024 + o*512]);
    }

    // A fragments: C[w] half-slab, loaded once (L2-resident)
    half8 A[4][4];
    {
        const _Float16* Crow = Ch + ((size_t)w*128 + dh*64 + lr)*128 + lg*8;
        #pragma unroll
        for (int m = 0; m < 4; ++m)
            #pragma unroll
            for (int kk = 0; kk < 4; ++kk)
                A[m][kk] = *(const half8*)(Crow + (size_t)m*16*128 + kk*32);
    }
    __syncthreads();

    for (int t = 0; t < 16; ++t) {
        int buf = t & 1;
        if (t < 15) {
            const _Float16* g = qrows + (size_t)(t+1)*8192 + wv*1024 + lane*8;
            #pragma unroll
            for (int o = 0; o < 2; ++o)
                gload_lds16(g + o*512, &qTb[buf^1][wv*1024 + o*512]);
        }
        const _Float16* qb = qTb[buf];
        f32x4 acc[4][4];
        #pragma unroll
        for (int m = 0; m < 4; ++m)
            #pragma unroll
            for (int n = 0; n < 4; ++n) acc[m][n] = (f32x4){0.f,0.f,0.f,0.f};
        #pragma unroll
        for (int kk = 0; kk < 4; ++kk) {
            half8 Bf[4];
            #pragma unroll
            for (int n = 0; n < 4; ++n) {
                int i = n*16 + lr;
                Bf[n] = *(const half8*)(qb + i*128 + ((kk*32 + lg*8) ^ ((i&7)<<3)));
            }
            #pragma unroll
            for (int m = 0; m < 4; ++m)
                #pragma unroll
                for (int n = 0; n < 4; ++n)
                    acc[m][n] = __builtin_amdgcn_mfma_f32_16x16x32_f16(A[m][kk], Bf[n], acc[m][n], 0,0,0);
        }
        // diag contraction: s[n] = sum over this wave's 64 d of q[d,i]*T[d,i]
        float s[4] = {0.f,0.f,0.f,0.f};
        #pragma unroll
        for (int n = 0; n < 4; ++n) {
            int i = n*16 + lr;
            const _Float16* qrow = qb + i*128;
            int sw = (i&7) << 3;
            #pragma unroll
            for (int m = 0; m < 4; ++m) {
                int c0 = dh*64 + m*16 + lg*4;
                half4 hq = *(const half4*)(qrow + (c0 ^ sw));
                f32x4 a = acc[m][n];
                s[n] = fmaf((float)hq[0], a[0], s[n]);
                s[n] = fmaf((float)hq[1], a[1], s[n]);
                s[n] = fmaf((float)hq[2], a[2], s[n]);
                s[n] = fmaf((float)hq[3], a[3], s[n]);
            }
        }
        #pragma unroll
        for (int n = 0; n < 4; ++n) {
            s[n] += __shfl_xor(s[n], 16);
            s[n] += __shfl_xor(s[n], 32);
        }
        if (lane < 16) {
            #pragma unroll
            for (int n = 0; n < 4; ++n) simbuf[wv][n*16 + lr] = s[n];
        }
        __syncthreads();
        if (tid < 256) {
            int wl = tid >> 6, i = tid & 63;
            out[((size_t)b*W_CLS + wq*4 + wl)*HW + t*64 + i] = simbuf[wl*2][i] + simbuf[wl*2+1][i];
        }
        __syncthreads();
    }
}

// ================= fallback path (round-2 kernels, small ws) =================

__global__ __launch_bounds__(256) void mean_kernel_f(const float* __restrict__ x2,
                                                     float* __restrict__ mean) {
    int wc = blockIdx.x;
    int w  = wc >> 7, c = wc & 127;
    const float* base = x2 + ((size_t)(w * SHOT) * C_CH + c) * HW;
    int tid = threadIdx.x;
    float sum = 0.f;
    for (int s = 0; s < SHOT; ++s) {
        const float* row = base + (size_t)s * C_CH * HW;
        for (int p = tid; p < HW; p += 256) sum += row[p];
    }
    for (int off = 32; off; off >>= 1) sum += __shfl_down(sum, off, 64);
    __shared__ float red[4];
    int lane = tid & 63, wv = tid >> 6;
    if (lane == 0) red[wv] = sum;
    __syncthreads();
    if (tid == 0) mean[wc] = (red[0] + red[1] + red[2] + red[3]) * (1.0f / NSAMP);
}

__global__ __launch_bounds__(256) void cova_kernel_f(const float* __restrict__ x2,
                                                     const float* __restrict__ mean,
                                                     _Float16* __restrict__ covah) {
    int bid = blockIdx.x;
    int w  = bid >> 4;
    int c0 = ((bid >> 2) & 3) * 32;
    int d0 = (bid & 3) * 32;
    __shared__ float As[32][33];
    __shared__ float Bs[32][33];
    int tid = threadIdx.x;
    int ty = tid >> 4, tx = tid & 15;
    int lrr = tid >> 3, lc = (tid & 7) * 4;
    const float* base = x2 + (size_t)w * SHOT * C_CH * HW;
    float acc00 = 0.f, acc01 = 0.f, acc10 = 0.f, acc11 = 0.f;
    for (int k0 = 0; k0 < NSAMP; k0 += 32) {
        int s = k0 >> 10, p = k0 & 1023;
        const float4 a4 = *(const float4*)(base + ((size_t)s * C_CH + (c0 + lrr)) * HW + p + lc);
        const float4 b4 = *(const float4*)(base + ((size_t)s * C_CH + (d0 + lrr)) * HW + p + lc);
        As[lrr][lc+0] = a4.x; As[lrr][lc+1] = a4.y; As[lrr][lc+2] = a4.z; As[lrr][lc+3] = a4.w;
        Bs[lrr][lc+0] = b4.x; Bs[lrr][lc+1] = b4.y; Bs[lrr][lc+2] = b4.z; Bs[lrr][lc+3] = b4.w;
        __syncthreads();
        #pragma unroll
        for (int kk = 0; kk < 32; ++kk) {
            float a0 = As[ty*2][kk],   a1 = As[ty*2+1][kk];
            float b0 = Bs[tx*2][kk],   b1 = Bs[tx*2+1][kk];
            acc00 = fmaf(a0, b0, acc00);
            acc01 = fmaf(a0, b1, acc01);
            acc10 = fmaf(a1, b0, acc10);
            acc11 = fmaf(a1, b1, acc11);
        }
        __syncthreads();
    }
    const float inv = 1.0f / (NSAMP - 1);
    int c = c0 + ty * 2, d = d0 + tx * 2;
    float mc0 = mean[w*128 + c],     mc1 = mean[w*128 + c + 1];
    float md0 = mean[w*128 + d],     md1 = mean[w*128 + d + 1];
    _Float16* o = covah + ((size_t)w * 128 + c) * 128 + d;
    o[0]   = (_Float16)((acc00 - (float)NSAMP * mc0 * md0) * inv);
    o[1]   = (_Float16)((acc01 - (float)NSAMP * mc0 * md1) * inv);
    o[128] = (_Float16)((acc10 - (float)NSAMP * mc1 * md0) * inv);
    o[129] = (_Float16)((acc11 - (float)NSAMP * mc1 * md1) * inv);
}

#define LDQ 136
__global__ __launch_bounds__(512) void sim_kernel_f(const float* __restrict__ x1,
                                                    const _Float16* __restrict__ Ch,
                                                    const float* __restrict__ rn,
                                                    float* __restrict__ out) {
    __shared__ _Float16 qT[128][LDQ];
    __shared__ float simbuf[2][128];
    int tid = threadIdx.x;
    int bq  = blockIdx.x;
    int b   = bq >> 3;
    int i0  = (bq & 7) * 128;
    {
        int c  = tid >> 2;
        int iq = (tid & 3) * 32;
        const float* src = x1 + ((size_t)b * C_CH + c) * HW + i0 + iq;
        float scale = rn[b * C_CH + c];
        #pragma unroll
        for (int j4 = 0; j4 < 8; ++j4) {
            f32x4 v = *(const f32x4*)(src + j4 * 4);
            qT[iq + j4*4 + 0][c] = (_Float16)(v.x * scale);
            qT[iq + j4*4 + 1][c] = (_Float16)(v.y * scale);
            qT[iq + j4*4 + 2][c] = (_Float16)(v.z * scale);
            qT[iq + j4*4 + 3][c] = (_Float16)(v.w * scale);
        }
    }
    __syncthreads();
    int lane = tid & 63;
    int wv   = tid >> 6;
    int mh   = wv >> 2;
    int nq   = wv & 3;
    int d0w  = mh * 64;
    int iw   = nq * 32;
    int lr   = lane & 15;
    int lg   = lane >> 4;
    float qd[4][2][4];
    #pragma unroll
    for (int m = 0; m < 4; ++m)
        #pragma unroll
        for (int n = 0; n < 2; ++n) {
            half4 hq = *(const half4*)&qT[iw + n*16 + lr][d0w + m*16 + lg*4];
            qd[m][n][0] = (float)hq[0];
            qd[m][n][1] = (float)hq[1];
            qd[m][n][2] = (float)hq[2];
            qd[m][n][3] = (float)hq[3];
        }
    for (int w = 0; w < W_CLS; ++w) {
        const _Float16* Cw = Ch + (size_t)w * C_CH * C_CH;
        half8 A[4][4];
        #pragma unroll
        for (int m = 0; m < 4; ++m)
            #pragma unroll
            for (int k = 0; k < 4; ++k)
                A[m][k] = *(const half8*)(Cw + (size_t)(d0w + m*16 + lr) * C_CH + k*32 + lg*8);
        f32x4 acc[4][2];
        #pragma unroll
        for (int m = 0; m < 4; ++m)
            #pragma unroll
            for (int n = 0; n < 2; ++n)
                acc[m][n] = (f32x4){0.f, 0.f, 0.f, 0.f};
        #pragma unroll
        for (int k = 0; k < 4; ++k) {
            #pragma unroll
            for (int n = 0; n < 2; ++n) {
                half8 Bf = *(const half8*)&qT[iw + n*16 + lr][k*32 + lg*8];
                #pragma unroll
                for (int m = 0; m < 4; ++m)
                    acc[m][n] = __builtin_amdgcn_mfma_f32_16x16x32_f16(A[m][k], Bf, acc[m][n], 0, 0, 0);
            }
        }
        float s0 = 0.f, s1 = 0.f;
        #pragma unroll
        for (int m = 0; m < 4; ++m) {
            #pragma unroll
            for (int r = 0; r < 4; ++r) {
                s0 = fmaf(qd[m][0][r], acc[m][0][r], s0);
                s1 = fmaf(qd[m][1][r], acc[m][1][r], s1);
            }
        }
        s0 += __shfl_xor(s0, 16); s0 += __shfl_xor(s0, 32);
        s1 += __shfl_xor(s1, 16); s1 += __shfl_xor(s1, 32);
        if (lane < 16) {
            simbuf[mh][iw + 0*16 + lane] = s0;
            simbuf[mh][iw + 1*16 + lane] = s1;
        }
        __syncthreads();
        if (tid < 128)
            out[((size_t)b * W_CLS + w) * HW + i0 + tid] = simbuf[0][tid] + simbuf[1][tid];
        __syncthreads();
    }
}

// ================= host =================

extern "C" void kernel_launch(void* const* d_in, const int* in_sizes, int n_in,
                              void* d_out, int out_size, void* d_ws, size_t ws_size,
                              hipStream_t stream) {
    (void)in_sizes; (void)n_in; (void)out_size;
    const float* x1 = (const float*)d_in[0];   // [256,128,32,32]
    const float* x2 = (const float*)d_in[1];   // [16,8,128,32,32]
    float* out = (float*)d_out;

    char* ws = (char*)d_ws;
    const size_t OFF_QHT = 0;                          // 256*1024*128 fp16 = 64 MB
    const size_t OFF_PG  = 67108864;                   // 16*16*128*128 f32 = 16 MB
    const size_t OFF_PM  = OFF_PG + 16777216;          // 16*16*128 f32
    const size_t OFF_CH  = OFF_PM + 131072;            // 16*128*128 fp16
    const size_t OFF_RN  = OFF_CH + 524288;            // 256*128 f32
    const size_t NEED    = OFF_RN + 131072;

    if (ws_size >= NEED) {
        _Float16* qhT = (_Float16*)(ws + OFF_QHT);
        float*    PG  = (float*)(ws + OFF_PG);
        float*    pm  = (float*)(ws + OFF_PM);
        _Float16* Ch  = (_Float16*)(ws + OFF_CH);
        float*    rn  = (float*)(ws + OFF_RN);
        cova_part  <<<256,            512, 0, stream>>>(x2, PG, pm);
        cova_reduce<<<128,            256, 0, stream>>>(PG, pm, Ch);
        rnorm_kernel<<<B_Q*C_CH/4,    256, 0, stream>>>(x1, rn);
        qconv_kernel<<<B_Q*16,        256, 0, stream>>>(x1, rn, qhT);
        sim_kernel <<<B_Q*4,          512, 0, stream>>>(qhT, Ch, out);
    } else {
        float*    mean = (float*)ws;                       // 2048 f32
        float*    rn   = mean + W_CLS*C_CH;                // 32768 f32
        _Float16* Ch   = (_Float16*)(rn + B_Q*C_CH);       // 512 KB
        mean_kernel_f<<<W_CLS*C_CH,   256, 0, stream>>>(x2, mean);
        cova_kernel_f<<<W_CLS*16,     256, 0, stream>>>(x2, mean, Ch);
        rnorm_kernel <<<B_Q*C_CH/4,   256, 0, stream>>>(x1, rn);
        sim_kernel_f <<<B_Q*8,        512, 0, stream>>>(x1, Ch, rn, out);
    }
}

// Round 4
// 220.376 us; speedup vs baseline: 13.5117x; 1.0271x over previous
//
#include <hip/hip_runtime.h>

typedef _Float16 half8 __attribute__((ext_vector_type(8)));
typedef _Float16 half4 __attribute__((ext_vector_type(4)));
typedef float    f32x4 __attribute__((ext_vector_type(4)));

#define W_CLS 16
#define SHOT  8
#define C_CH  128
#define HW    1024
#define NSAMP (SHOT*HW)   /* 8192 */
#define B_Q   256

// async global->LDS, 16B per lane; LDS dest = wave-uniform base (+lane*16 by HW)
__device__ __forceinline__ void gload_lds16(const _Float16* g, _Float16* l) {
    __builtin_amdgcn_global_load_lds((const __attribute__((address_space(1))) unsigned int*)g,
                                     (__attribute__((address_space(3))) unsigned int*)l,
                                     16, 0, 0);
}

// ================= primary path =================

// ---- cova_part: per (w, k-split) partial gram via fp16 MFMA + mean partials ----
// grid 256 = 16 w x 16 ks (ks = shot*2 + p-half, K=512 per block), block 512
__global__ __launch_bounds__(512) void cova_part(const float* __restrict__ x2,
                                                 float* __restrict__ PG,
                                                 float* __restrict__ pmean) {
    __shared__ _Float16 XT[2][128*72];   // [c][p] fp16, pad 72 (conflict-free frags)
    __shared__ float mred[128][4];
    int tid = threadIdx.x;
    int w = blockIdx.x >> 4, ks = blockIdx.x & 15;
    int s = ks >> 1, p00 = (ks & 1) * 512;
    int c = tid >> 2, ph = (tid & 3) * 16;
    const float* src = x2 + (((size_t)(w*SHOT + s))*C_CH + c)*HW + p00 + ph;
    int lane = tid & 63, wv = tid >> 6;
    int lr = lane & 15, lg = lane >> 4;
    int mt0 = (wv & 3)*2, nt0 = (wv >> 2)*4;

    float msum = 0.f;
    f32x4 acc[2][4];
    #pragma unroll
    for (int mm = 0; mm < 2; ++mm)
        #pragma unroll
        for (int nn = 0; nn < 4; ++nn) acc[mm][nn] = (f32x4){0.f,0.f,0.f,0.f};

    float4 rg[4];
    #pragma unroll
    for (int j = 0; j < 4; ++j) rg[j] = *(const float4*)(src + j*4);
    #pragma unroll
    for (int j = 0; j < 4; ++j) {
        msum += rg[j].x + rg[j].y + rg[j].z + rg[j].w;
        half4 h = {(_Float16)rg[j].x, (_Float16)rg[j].y, (_Float16)rg[j].z, (_Float16)rg[j].w};
        *(half4*)(&XT[0][c*72 + ph + j*4]) = h;
    }
    __syncthreads();

    for (int ch = 0; ch < 8; ++ch) {
        int buf = ch & 1;
        if (ch < 7) {
            #pragma unroll
            for (int j = 0; j < 4; ++j) rg[j] = *(const float4*)(src + (ch+1)*64 + j*4);
        }
        const _Float16* xb = XT[buf];
        #pragma unroll
        for (int kk = 0; kk < 2; ++kk) {
            half8 Bv[4], Av[2];
            #pragma unroll
            for (int nn = 0; nn < 4; ++nn)
                Bv[nn] = *(const half8*)(xb + ((nt0+nn)*16 + lr)*72 + kk*32 + lg*8);
            #pragma unroll
            for (int mm = 0; mm < 2; ++mm)
                Av[mm] = *(const half8*)(xb + ((mt0+mm)*16 + lr)*72 + kk*32 + lg*8);
            #pragma unroll
            for (int mm = 0; mm < 2; ++mm)
                #pragma unroll
                for (int nn = 0; nn < 4; ++nn)
                    acc[mm][nn] = __builtin_amdgcn_mfma_f32_16x16x32_f16(Av[mm], Bv[nn], acc[mm][nn], 0,0,0);
        }
        if (ch < 7) {
            #pragma unroll
            for (int j = 0; j < 4; ++j) {
                msum += rg[j].x + rg[j].y + rg[j].z + rg[j].w;
                half4 h = {(_Float16)rg[j].x, (_Float16)rg[j].y, (_Float16)rg[j].z, (_Float16)rg[j].w};
                *(half4*)(&XT[buf^1][c*72 + ph + j*4]) = h;
            }
        }
        __syncthreads();
    }

    mred[c][tid & 3] = msum;
    __syncthreads();
    if (tid < 128)
        pmean[((size_t)w*16 + ks)*128 + tid] = mred[tid][0]+mred[tid][1]+mred[tid][2]+mred[tid][3];

    float* pg = PG + ((size_t)w*16 + ks)*16384;
    #pragma unroll
    for (int mm = 0; mm < 2; ++mm)
        #pragma unroll
        for (int nn = 0; nn < 4; ++nn)
            #pragma unroll
            for (int r = 0; r < 4; ++r) {
                int cr = (mt0+mm)*16 + lg*4 + r;
                int d  = (nt0+nn)*16 + lr;
                pg[cr*128 + d] = acc[mm][nn][r];
            }
}

// ---- cova_reduce: sum 16 partials, mean-correct, write U = triu(C, half-diag) --
// grid 128 = 16 w x 8 row-groups, block 256
__global__ __launch_bounds__(256) void cova_reduce(const float* __restrict__ PG,
                                                   const float* __restrict__ pmean,
                                                   _Float16* __restrict__ Uh) {
    __shared__ float ms[128];
    int t = threadIdx.x;
    int w = blockIdx.x >> 3, rg = blockIdx.x & 7;
    if (t < 128) {
        float sum = 0.f;
        for (int ks = 0; ks < 16; ++ks) sum += pmean[((size_t)w*16 + ks)*128 + t];
        ms[t] = sum * (1.0f/NSAMP);
    }
    __syncthreads();
    const float* pg = PG + (size_t)w*16*16384;
    #pragma unroll
    for (int it = 0; it < 8; ++it) {
        int e = it*256 + t;
        int r = rg*16 + (e >> 7), d = e & 127;   // r = row, d = col
        float g = 0.f;
        for (int ks = 0; ks < 16; ++ks) g += pg[(size_t)ks*16384 + r*128 + d];
        float val = (g - (float)NSAMP*ms[r]*ms[d]) * (1.0f/(NSAMP-1));
        float uval = (d > r) ? val : ((d == r) ? 0.5f*val : 0.0f);
        Uh[((size_t)w*128 + r)*128 + d] = (_Float16)uval;
    }
}

// ---- rnorm: reciprocal L2 norm per (b,c) row of 1024 --------------------------
__global__ __launch_bounds__(256) void rnorm_kernel(const float* __restrict__ x1,
                                                    float* __restrict__ rn) {
    int row  = blockIdx.x * 4 + (threadIdx.x >> 6);
    int lane = threadIdx.x & 63;
    const float4* p = (const float4*)(x1 + (size_t)row * HW);
    float s = 0.f;
    #pragma unroll
    for (int it = 0; it < 4; ++it) {
        float4 v = p[lane + it * 64];
        s += v.x*v.x + v.y*v.y + v.z*v.z + v.w*v.w;
    }
    for (int off = 32; off; off >>= 1) s += __shfl_down(s, off, 64);
    if (lane == 0) rn[row] = 1.0f / sqrtf(s);
}

// ---- qconv: normalized fp16 q, transposed [b][i][c] with XOR-pre-swizzle ------
// grid 4096 = 256 b x 16 i-chunks of 64, block 256 (4 c-groups x 64 i-lanes)
__global__ __launch_bounds__(256) void qconv_kernel(const float* __restrict__ x1,
                                                    const float* __restrict__ rn,
                                                    _Float16* __restrict__ qhT) {
    int t = threadIdx.x; int lane = t & 63; int cg = t >> 6;
    int bid = blockIdx.x; int b = bid >> 4; int i0 = (bid & 15) * 64;
    int i = i0 + lane;
    const float* xb  = x1 + (size_t)b * C_CH * HW;
    const float* rnb = rn + b * C_CH;
    _Float16 hb[32];
    #pragma unroll
    for (int cc = 0; cc < 32; ++cc) {
        int c = cg*32 + cc;
        hb[cc] = (_Float16)(xb[(size_t)c * HW + i] * rnb[c]);
    }
    _Float16* orow = qhT + ((size_t)b * HW + i) * C_CH;
    #pragma unroll
    for (int j8 = 0; j8 < 4; ++j8) {
        half8 h8;
        #pragma unroll
        for (int e = 0; e < 8; ++e) h8[e] = hb[j8*8 + e];
        int c0 = (cg*32 + j8*8) ^ ((lane & 7) << 3);
        *(half8*)(orow + c0) = h8;
    }
}

// ---- sim: symmetric-U MFMA; wave = (w, i-half) owns all 8 m-tiles -------------
// grid 1024: b = bid&255, wq = bid>>8 (same-b blocks land on same XCD)
// block 512 = 8 waves = 4 w x 2 i-halves; 16 chunks of 64 i, LDS double-buffered
__global__ __launch_bounds__(512, 2) void sim_kernel(const _Float16* __restrict__ qhT,
                                                     const _Float16* __restrict__ Uh,
                                                     float* __restrict__ out) {
    __shared__ _Float16 qTb[2][64*128];
    int tid = threadIdx.x;
    int lane = tid & 63, wv = tid >> 6;
    int lr = lane & 15, lg = lane >> 4;
    int b  = blockIdx.x & 255;
    int wq = blockIdx.x >> 8;
    int w_l = wv >> 1, nh = wv & 1;
    int w = wq*4 + w_l;

    const _Float16* qrows = qhT + (size_t)b * HW * C_CH;

    // stage chunk 0 -> buf 0 (wave wv stages rows wv*8 .. wv*8+7)
    {
        const _Float16* g = qrows + wv*1024 + lane*8;
        #pragma unroll
        for (int o = 0; o < 2; ++o)
            gload_lds16(g + o*512, &qTb[0][wv*1024 + o*512]);
    }

    // A fragments: upper-tri tiles (m,kk), m <= 2kk+1 -> 20 frags, loaded once
    half8 A[20];
    {
        const _Float16* Ub = Uh + (size_t)w*128*128 + (size_t)lr*128 + lg*8;
        int idx = 0;
        #pragma unroll
        for (int kk = 0; kk < 4; ++kk)
            #pragma unroll
            for (int m = 0; m <= 2*kk+1; ++m) {
                A[idx] = *(const half8*)(Ub + (size_t)m*16*128 + kk*32);
                ++idx;
            }
    }
    __syncthreads();

    for (int t = 0; t < 16; ++t) {
        int buf = t & 1;
        if (t < 15) {
            const _Float16* g = qrows + (size_t)(t+1)*8192 + wv*1024 + lane*8;
            #pragma unroll
            for (int o = 0; o < 2; ++o)
                gload_lds16(g + o*512, &qTb[buf^1][wv*1024 + o*512]);
        }
        const _Float16* qb = qTb[buf];

        f32x4 acc[8][2];
        #pragma unroll
        for (int m = 0; m < 8; ++m)
            #pragma unroll
            for (int nn = 0; nn < 2; ++nn) acc[m][nn] = (f32x4){0.f,0.f,0.f,0.f};

        int idx = 0;
        #pragma unroll
        for (int kk = 0; kk < 4; ++kk) {
            half8 Bf[2];
            #pragma unroll
            for (int nn = 0; nn < 2; ++nn) {
                int i = nh*32 + nn*16 + lr;
                Bf[nn] = *(const half8*)(qb + i*128 + ((kk*32 + lg*8) ^ ((i&7)<<3)));
            }
            #pragma unroll
            for (int m = 0; m <= 2*kk+1; ++m) {
                #pragma unroll
                for (int nn = 0; nn < 2; ++nn)
                    acc[m][nn] = __builtin_amdgcn_mfma_f32_16x16x32_f16(A[idx], Bf[nn], acc[m][nn], 0,0,0);
                ++idx;
            }
        }

        // diag contraction over full d=128 (this wave owns all m): out = 2*q.T
        float sres[2];
        #pragma unroll
        for (int nn = 0; nn < 2; ++nn) {
            int i = nh*32 + nn*16 + lr;
            const _Float16* qrow = qb + i*128;
            int sw = (i&7) << 3;
            float s = 0.f;
            #pragma unroll
            for (int m = 0; m < 8; ++m) {
                half4 hq = *(const half4*)(qrow + ((m*16 + lg*4) ^ sw));
                f32x4 a = acc[m][nn];
                s = fmaf((float)hq[0], a[0], s);
                s = fmaf((float)hq[1], a[1], s);
                s = fmaf((float)hq[2], a[2], s);
                s = fmaf((float)hq[3], a[3], s);
            }
            s += __shfl_xor(s, 16);
            s += __shfl_xor(s, 32);
            sres[nn] = s;
        }
        if (lane < 16) {
            float* o = out + ((size_t)b*W_CLS + w)*HW + t*64 + nh*32;
            o[lr]      = 2.0f * sres[0];
            o[16 + lr] = 2.0f * sres[1];
        }
        __syncthreads();
    }
}

// ================= fallback path (round-2 kernels, small ws) =================

__global__ __launch_bounds__(256) void mean_kernel_f(const float* __restrict__ x2,
                                                     float* __restrict__ mean) {
    int wc = blockIdx.x;
    int w  = wc >> 7, c = wc & 127;
    const float* base = x2 + ((size_t)(w * SHOT) * C_CH + c) * HW;
    int tid = threadIdx.x;
    float sum = 0.f;
    for (int s = 0; s < SHOT; ++s) {
        const float* row = base + (size_t)s * C_CH * HW;
        for (int p = tid; p < HW; p += 256) sum += row[p];
    }
    for (int off = 32; off; off >>= 1) sum += __shfl_down(sum, off, 64);
    __shared__ float red[4];
    int lane = tid & 63, wv = tid >> 6;
    if (lane == 0) red[wv] = sum;
    __syncthreads();
    if (tid == 0) mean[wc] = (red[0] + red[1] + red[2] + red[3]) * (1.0f / NSAMP);
}

__global__ __launch_bounds__(256) void cova_kernel_f(const float* __restrict__ x2,
                                                     const float* __restrict__ mean,
                                                     _Float16* __restrict__ covah) {
    int bid = blockIdx.x;
    int w  = bid >> 4;
    int c0 = ((bid >> 2) & 3) * 32;
    int d0 = (bid & 3) * 32;
    __shared__ float As[32][33];
    __shared__ float Bs[32][33];
    int tid = threadIdx.x;
    int ty = tid >> 4, tx = tid & 15;
    int lrr = tid >> 3, lc = (tid & 7) * 4;
    const float* base = x2 + (size_t)w * SHOT * C_CH * HW;
    float acc00 = 0.f, acc01 = 0.f, acc10 = 0.f, acc11 = 0.f;
    for (int k0 = 0; k0 < NSAMP; k0 += 32) {
        int s = k0 >> 10, p = k0 & 1023;
        const float4 a4 = *(const float4*)(base + ((size_t)s * C_CH + (c0 + lrr)) * HW + p + lc);
        const float4 b4 = *(const float4*)(base + ((size_t)s * C_CH + (d0 + lrr)) * HW + p + lc);
        As[lrr][lc+0] = a4.x; As[lrr][lc+1] = a4.y; As[lrr][lc+2] = a4.z; As[lrr][lc+3] = a4.w;
        Bs[lrr][lc+0] = b4.x; Bs[lrr][lc+1] = b4.y; Bs[lrr][lc+2] = b4.z; Bs[lrr][lc+3] = b4.w;
        __syncthreads();
        #pragma unroll
        for (int kk = 0; kk < 32; ++kk) {
            float a0 = As[ty*2][kk],   a1 = As[ty*2+1][kk];
            float b0 = Bs[tx*2][kk],   b1 = Bs[tx*2+1][kk];
            acc00 = fmaf(a0, b0, acc00);
            acc01 = fmaf(a0, b1, acc01);
            acc10 = fmaf(a1, b0, acc10);
            acc11 = fmaf(a1, b1, acc11);
        }
        __syncthreads();
    }
    const float inv = 1.0f / (NSAMP - 1);
    int c = c0 + ty * 2, d = d0 + tx * 2;
    float mc0 = mean[w*128 + c],     mc1 = mean[w*128 + c + 1];
    float md0 = mean[w*128 + d],     md1 = mean[w*128 + d + 1];
    _Float16* o = covah + ((size_t)w * 128 + c) * 128 + d;
    o[0]   = (_Float16)((acc00 - (float)NSAMP * mc0 * md0) * inv);
    o[1]   = (_Float16)((acc01 - (float)NSAMP * mc0 * md1) * inv);
    o[128] = (_Float16)((acc10 - (float)NSAMP * mc1 * md0) * inv);
    o[129] = (_Float16)((acc11 - (float)NSAMP * mc1 * md1) * inv);
}

#define LDQ 136
__global__ __launch_bounds__(512) void sim_kernel_f(const float* __restrict__ x1,
                                                    const _Float16* __restrict__ Ch,
                                                    const float* __restrict__ rn,
                                                    float* __restrict__ out) {
    __shared__ _Float16 qT[128][LDQ];
    __shared__ float simbuf[2][128];
    int tid = threadIdx.x;
    int bq  = blockIdx.x;
    int b   = bq >> 3;
    int i0  = (bq & 7) * 128;
    {
        int c  = tid >> 2;
        int iq = (tid & 3) * 32;
        const float* src = x1 + ((size_t)b * C_CH + c) * HW + i0 + iq;
        float scale = rn[b * C_CH + c];
        #pragma unroll
        for (int j4 = 0; j4 < 8; ++j4) {
            f32x4 v = *(const f32x4*)(src + j4 * 4);
            qT[iq + j4*4 + 0][c] = (_Float16)(v.x * scale);
            qT[iq + j4*4 + 1][c] = (_Float16)(v.y * scale);
            qT[iq + j4*4 + 2][c] = (_Float16)(v.z * scale);
            qT[iq + j4*4 + 3][c] = (_Float16)(v.w * scale);
        }
    }
    __syncthreads();
    int lane = tid & 63;
    int wv   = tid >> 6;
    int mh   = wv >> 2;
    int nq   = wv & 3;
    int d0w  = mh * 64;
    int iw   = nq * 32;
    int lr   = lane & 15;
    int lg   = lane >> 4;
    float qd[4][2][4];
    #pragma unroll
    for (int m = 0; m < 4; ++m)
        #pragma unroll
        for (int n = 0; n < 2; ++n) {
            half4 hq = *(const half4*)&qT[iw + n*16 + lr][d0w + m*16 + lg*4];
            qd[m][n][0] = (float)hq[0];
            qd[m][n][1] = (float)hq[1];
            qd[m][n][2] = (float)hq[2];
            qd[m][n][3] = (float)hq[3];
        }
    for (int w = 0; w < W_CLS; ++w) {
        const _Float16* Cw = Ch + (size_t)w * C_CH * C_CH;
        half8 A[4][4];
        #pragma unroll
        for (int m = 0; m < 4; ++m)
            #pragma unroll
            for (int k = 0; k < 4; ++k)
                A[m][k] = *(const half8*)(Cw + (size_t)(d0w + m*16 + lr) * C_CH + k*32 + lg*8);
        f32x4 acc[4][2];
        #pragma unroll
        for (int m = 0; m < 4; ++m)
            #pragma unroll
            for (int n = 0; n < 2; ++n)
                acc[m][n] = (f32x4){0.f, 0.f, 0.f, 0.f};
        #pragma unroll
        for (int k = 0; k < 4; ++k) {
            #pragma unroll
            for (int n = 0; n < 2; ++n) {
                half8 Bf = *(const half8*)&qT[iw + n*16 + lr][k*32 + lg*8];
                #pragma unroll
                for (int m = 0; m < 4; ++m)
                    acc[m][n] = __builtin_amdgcn_mfma_f32_16x16x32_f16(A[m][k], Bf, acc[m][n], 0, 0, 0);
            }
        }
        float s0 = 0.f, s1 = 0.f;
        #pragma unroll
        for (int m = 0; m < 4; ++m) {
            #pragma unroll
            for (int r = 0; r < 4; ++r) {
                s0 = fmaf(qd[m][0][r], acc[m][0][r], s0);
                s1 = fmaf(qd[m][1][r], acc[m][1][r], s1);
            }
        }
        s0 += __shfl_xor(s0, 16); s0 += __shfl_xor(s0, 32);
        s1 += __shfl_xor(s1, 16); s1 += __shfl_xor(s1, 32);
        if (lane < 16) {
            simbuf[mh][iw + 0*16 + lane] = s0;
            simbuf[mh][iw + 1*16 + lane] = s1;
        }
        __syncthreads();
        if (tid < 128)
            out[((size_t)b * W_CLS + w) * HW + i0 + tid] = simbuf[0][tid] + simbuf[1][tid];
        __syncthreads();
    }
}

// ================= host =================

extern "C" void kernel_launch(void* const* d_in, const int* in_sizes, int n_in,
                              void* d_out, int out_size, void* d_ws, size_t ws_size,
                              hipStream_t stream) {
    (void)in_sizes; (void)n_in; (void)out_size;
    const float* x1 = (const float*)d_in[0];   // [256,128,32,32]
    const float* x2 = (const float*)d_in[1];   // [16,8,128,32,32]
    float* out = (float*)d_out;

    char* ws = (char*)d_ws;
    const size_t OFF_QHT = 0;                          // 256*1024*128 fp16 = 64 MB
    const size_t OFF_PG  = 67108864;                   // 16*16*128*128 f32 = 16 MB
    const size_t OFF_PM  = OFF_PG + 16777216;          // 16*16*128 f32
    const size_t OFF_CH  = OFF_PM + 131072;            // 16*128*128 fp16
    const size_t OFF_RN  = OFF_CH + 524288;            // 256*128 f32
    const size_t NEED    = OFF_RN + 131072;

    if (ws_size >= NEED) {
        _Float16* qhT = (_Float16*)(ws + OFF_QHT);
        float*    PG  = (float*)(ws + OFF_PG);
        float*    pm  = (float*)(ws + OFF_PM);
        _Float16* Uh  = (_Float16*)(ws + OFF_CH);
        float*    rn  = (float*)(ws + OFF_RN);
        cova_part  <<<256,            512, 0, stream>>>(x2, PG, pm);
        cova_reduce<<<128,            256, 0, stream>>>(PG, pm, Uh);
        rnorm_kernel<<<B_Q*C_CH/4,    256, 0, stream>>>(x1, rn);
        qconv_kernel<<<B_Q*16,        256, 0, stream>>>(x1, rn, qhT);
        sim_kernel <<<B_Q*4,          512, 0, stream>>>(qhT, Uh, out);
    } else {
        float*    mean = (float*)ws;                       // 2048 f32
        float*    rn   = mean + W_CLS*C_CH;                // 32768 f32
        _Float16* Ch   = (_Float16*)(rn + B_Q*C_CH);       // 512 KB
        mean_kernel_f<<<W_CLS*C_CH,   256, 0, stream>>>(x2, mean);
        cova_kernel_f<<<W_CLS*16,     256, 0, stream>>>(x2, mean, Ch);
        rnorm_kernel <<<B_Q*C_CH/4,   256, 0, stream>>>(x1, rn);
        sim_kernel_f <<<B_Q*8,        512, 0, stream>>>(x1, Ch, rn, out);
    }
}